// Round 1
// 179.953 us; speedup vs baseline: 1.0903x; 1.0903x over previous
//
#include <hip/hip_runtime.h>
#include <hip/hip_bf16.h>

#define N_SRC 50000
#define N_DST 50000
#define N_EDGES 600000
#define IN_FEAT 128
#define OUT_FEAT 128
#define CAP 64                          // per-dst bucket capacity (Poisson(12), P(deg>64)~1e-30)

typedef __attribute__((ext_vector_type(8))) short short8;   // 8 bf16 = 4 VGPRs
typedef __attribute__((ext_vector_type(4))) float float4v;  // MFMA C/D
typedef __attribute__((ext_vector_type(4))) float f32x4;

#define FILL_BLOCKS ((N_EDGES + 255) / 256)   // 2344
#define HS4 (N_SRC * IN_FEAT / 4)             // 1,600,000 float4s per matrix
#define CVT_BLOCKS (HS4 / 256)                // 6250
#define W_BLOCKS 16                           // 4096 8-elem chunks / 256
#define K1_GRID (FILL_BLOCKS + 2 * CVT_BLOCKS + W_BLOCKS)

// ---------------------------------------------------------------------------
// K1 (split-grid fusion of four independent jobs; fill FIRST so its atomic
// stream starts immediately, streaming cvt work hides behind it):
//   [0, FILL)            bucket-fill: p=atomicAdd(deg[d]); permu[d*CAP+p]=src (ushort)
//   [FILL, +CVT)         f32->bf16 convert h_s -> hsb
//   [FILL+CVT, +CVT)     f32->bf16 convert h_d -> hdb
//   [.., +16)            W f32 -> fragment-major bf16 wfrag (GEMM stages via memcpy)
// All stream-once f32/int inputs use nontemporal loads to keep L2 for permu.
// ---------------------------------------------------------------------------
__global__ __launch_bounds__(256) void fill_cvt_kernel(
    const float* __restrict__ h_s, const float* __restrict__ h_d,
    const float* __restrict__ W,
    const int* __restrict__ src, const int* __restrict__ dst,
    int* __restrict__ deg, ushort* __restrict__ permu,
    ushort* __restrict__ hsb, ushort* __restrict__ hdb,
    ushort* __restrict__ wfrag)
{
    int bid = blockIdx.x;
    int tid = threadIdx.x;

    if (bid < FILL_BLOCKS) {
        int e = bid * 256 + tid;
        if (e < N_EDGES) {
            int s = __builtin_nontemporal_load(src + e);
            int d = __builtin_nontemporal_load(dst + e);
            int p = atomicAdd(&deg[d], 1);
            if (p < CAP) permu[(size_t)d * CAP + p] = (ushort)s;
        }
        return;
    }
    bid -= FILL_BLOCKS;

    if (bid < 2 * CVT_BLOCKS) {
        bool first = (bid < CVT_BLOCKS);
        const float* in = first ? h_s : h_d;
        ushort* outp    = first ? hsb : hdb;
        int idx = (first ? bid : bid - CVT_BLOCKS) * 256 + tid;
        f32x4 v = __builtin_nontemporal_load((const f32x4*)in + idx);
        __hip_bfloat16 o[4];
        o[0] = __float2bfloat16(v.x);
        o[1] = __float2bfloat16(v.y);
        o[2] = __float2bfloat16(v.z);
        o[3] = __float2bfloat16(v.w);
        *(ushort4*)(outp + (size_t)idx * 4) = *(ushort4*)o;
        return;
    }
    bid -= 2 * CVT_BLOCKS;

    // ---- W convert to fragment-major bf16 (exact layout the GEMM ds_reads):
    // chunk c: f=c>>6 (=ks*8+nt), l=c&63; elem = W[nt*16+(l&15)][ks*32+(l>>4)*8 ..+8]
    int c = bid * 256 + tid;              // [0, 4096)
    int f  = c >> 6;
    int l  = c & 63;
    int ks = f >> 3;
    int nt = f & 7;
    int row = nt * 16 + (l & 15);
    int col = ks * 32 + (l >> 4) * 8;
    const float* wp = W + (size_t)row * 256 + col;
    f32x4 w0 = __builtin_nontemporal_load((const f32x4*)wp);
    f32x4 w1 = __builtin_nontemporal_load((const f32x4*)wp + 1);
    __hip_bfloat16 o[8];
    o[0] = __float2bfloat16(w0.x); o[1] = __float2bfloat16(w0.y);
    o[2] = __float2bfloat16(w0.z); o[3] = __float2bfloat16(w0.w);
    o[4] = __float2bfloat16(w1.x); o[5] = __float2bfloat16(w1.y);
    o[6] = __float2bfloat16(w1.z); o[7] = __float2bfloat16(w1.w);
    *(short8*)(wfrag + (size_t)c * 8) = *(short8*)o;
}

// ---------------------------------------------------------------------------
// K2: gather-mean, one wave per dst row, bf16 in -> f32 acc -> bf16 out.
// Bucketed permu (ushort, CAP=64): row's srcs at permu[row*CAP .. +deg[row]).
// ---------------------------------------------------------------------------
__global__ __launch_bounds__(256) void gather_kernel(
    const ushort* __restrict__ hsb, const int* __restrict__ deg,
    const ushort* __restrict__ permu, ushort* __restrict__ neighb)
{
    int wave = threadIdx.x >> 6;
    int lane = threadIdx.x & 63;
    int row  = blockIdx.x * 4 + wave;
    if (row >= N_DST) return;

    int dg  = deg[row];
    int dgr = (dg < CAP) ? dg : CAP;     // paranoia clamp (overflow ~impossible)
    const ushort* prow = permu + (size_t)row * CAP;
    int s0 = (dgr > 0) ? (int)prow[0] : 0;

    float ax = 0.f, ay = 0.f;
    for (int j = 0; j < dgr; j += 8) {
        // uniform 8-B vector loads of the bucket (row extent is 64 slots, so
        // j..j+7 is always in-bounds; garbage slots masked below)
        ushort4 pa = *(const ushort4*)(prow + j);
        ushort4 pb = *(const ushort4*)(prow + j + 4);
        int t[8] = {pa.x, pa.y, pa.z, pa.w, pb.x, pb.y, pb.z, pb.w};
        int   s[8];
        float m[8];
#pragma unroll
        for (int q = 0; q < 8; ++q) {
            bool ok = (j + q < dgr);
            s[q] = ok ? t[q] : s0;
            m[q] = ok ? 1.f : 0.f;
        }
        ushort2 u[8];
#pragma unroll
        for (int q = 0; q < 8; ++q)
            u[q] = ((const ushort2*)(hsb + (size_t)s[q] * IN_FEAT))[lane];
#pragma unroll
        for (int q = 0; q < 8; ++q) {
            ax += m[q] * __uint_as_float((unsigned)u[q].x << 16);
            ay += m[q] * __uint_as_float((unsigned)u[q].y << 16);
        }
    }
    float inv = (dg > 0) ? (1.0f / (float)dg) : 0.0f;
    __hip_bfloat16 ox = __float2bfloat16(ax * inv);
    __hip_bfloat16 oy = __float2bfloat16(ay * inv);
    ushort2 o = make_ushort2(*(ushort*)&ox, *(ushort*)&oy);
    ((ushort2*)(neighb + (size_t)row * IN_FEAT))[lane] = o;
}

// ---------------------------------------------------------------------------
// K3: MFMA bf16 GEMM, all operands pre-converted:
//   out = [hdb | neighb] @ wfrag.T + b       (f32 out)
// Block: 256 thr / 4 waves, 128 rows x 128 cols. Wave: 32 rows (2 m-frags).
// W staging is now a straight 64 KB bf16 copy (fragment-major precomputed).
// A-frags are direct short8 loads — zero cvt VALU in the hot loop.
// ---------------------------------------------------------------------------
__global__ __launch_bounds__(256) void gemm_mfma_kernel(
    const ushort* __restrict__ hdb, const ushort* __restrict__ neighb,
    const ushort* __restrict__ wfrag, const float* __restrict__ b,
    float* __restrict__ out)
{
    __shared__ ushort sWb[64 * 64 * 8];   // 64 KB

    int tid  = threadIdx.x;
    int wave = tid >> 6;
    int lane = tid & 63;
    int lm   = lane & 15;
    int lk   = (lane >> 4) * 8;

    // ---- stage pre-converted W into LDS (16B per thread per iter) ----
#pragma unroll
    for (int i = 0; i < 16; ++i) {
        int c = i * 256 + tid;
        *(short8*)(sWb + (size_t)c * 8) = *(const short8*)(wfrag + (size_t)c * 8);
    }
    __syncthreads();

    int row0 = blockIdx.x * 128 + wave * 32;

    float4v acc0[8], acc1[8];
#pragma unroll
    for (int nt = 0; nt < 8; ++nt) {
        acc0[nt] = (float4v){0.f, 0.f, 0.f, 0.f};
        acc1[nt] = (float4v){0.f, 0.f, 0.f, 0.f};
    }

    int ar0 = row0 + lm;       ar0 = (ar0 < N_DST) ? ar0 : (N_DST - 1);
    int ar1 = row0 + 16 + lm;  ar1 = (ar1 < N_DST) ? ar1 : (N_DST - 1);
    const ushort* a0h = hdb    + (size_t)ar0 * IN_FEAT + lk;
    const ushort* a1h = hdb    + (size_t)ar1 * IN_FEAT + lk;
    const ushort* a0n = neighb + (size_t)ar0 * IN_FEAT + lk;
    const ushort* a1n = neighb + (size_t)ar1 * IN_FEAT + lk;

#pragma unroll
    for (int ks = 0; ks < 8; ++ks) {
        int koff = (ks & 3) * 32;
        short8 af0 = (ks < 4) ? *(const short8*)(a0h + koff)
                              : *(const short8*)(a0n + koff);
        short8 af1 = (ks < 4) ? *(const short8*)(a1h + koff)
                              : *(const short8*)(a1n + koff);
#pragma unroll
        for (int nt = 0; nt < 8; ++nt) {
            short8 bf = *(const short8*)(sWb + ((size_t)(ks * 8 + nt) * 64 + lane) * 8);
            acc0[nt] = __builtin_amdgcn_mfma_f32_16x16x32_bf16(af0, bf, acc0[nt], 0, 0, 0);
            acc1[nt] = __builtin_amdgcn_mfma_f32_16x16x32_bf16(af1, bf, acc1[nt], 0, 0, 0);
        }
    }

    // ---- epilogue: C/D layout col=lane&15, row=(lane>>4)*4+reg ----
    int orow0 = row0 + (lane >> 4) * 4;
#pragma unroll
    for (int nt = 0; nt < 8; ++nt) {
        int col = nt * 16 + lm;
        float bias = b[col];
#pragma unroll
        for (int r = 0; r < 4; ++r) {
            int oa = orow0 + r;
            int ob = oa + 16;
            if (oa < N_DST) out[(size_t)oa * OUT_FEAT + col] = acc0[nt][r] + bias;
            if (ob < N_DST) out[(size_t)ob * OUT_FEAT + col] = acc1[nt][r] + bias;
        }
    }
}

extern "C" void kernel_launch(void* const* d_in, const int* in_sizes, int n_in,
                              void* d_out, int out_size, void* d_ws, size_t ws_size,
                              hipStream_t stream) {
    const float* h_s = (const float*)d_in[0];
    const float* h_d = (const float*)d_in[1];
    const int*   src = (const int*)d_in[2];
    const int*   dst = (const int*)d_in[3];
    const float* W   = (const float*)d_in[4];
    const float* b   = (const float*)d_in[5];
    float* out = (float*)d_out;

    // workspace layout (~45 MB), all 16-B aligned:
    //   deg    int[50000]            @ 0          (200,000 B)
    //   permu  ushort[50000*64]      @ 200,000    (6,400,000 B)
    //   hsb    ushort[50000*128]     @ 6,600,000  (12,800,000 B)
    //   hdb    ushort[50000*128]     @ 19,400,000 (12,800,000 B)
    //   neighb ushort[50000*128]     @ 32,200,000 (12,800,000 B)
    //   wfrag  ushort[32768]         @ 45,000,000 (65,536 B)
    char* ws = (char*)d_ws;
    int*    deg    = (int*)ws;
    ushort* permu  = (ushort*)(ws + 200000);
    ushort* hsb    = (ushort*)(ws + 6600000);
    ushort* hdb    = (ushort*)(ws + 19400000);
    ushort* neighb = (ushort*)(ws + 32200000);
    ushort* wfrag  = (ushort*)(ws + 45000000);

    hipMemsetAsync(deg, 0, N_DST * sizeof(int), stream);

    fill_cvt_kernel<<<K1_GRID, 256, 0, stream>>>(
        h_s, h_d, W, src, dst, deg, permu, hsb, hdb, wfrag);
    gather_kernel<<<(N_DST + 3) / 4, 256, 0, stream>>>(
        hsb, deg, permu, neighb);
    gemm_mfma_kernel<<<(N_DST + 127) / 128, 256, 0, stream>>>(
        hdb, neighb, wfrag, b, out);
}